// Round 6
// baseline (2836.560 us; speedup 1.0000x reference)
//
#include <hip/hip_runtime.h>
#include <hip/hip_bf16.h>
#include <math.h>

#define DIM   384
#define HEADS 12
#define HD    32
#define WIN   7
#define NPIX  49
#define IMG   56
#define NWIN  1024   // 16 * 8 * 8
#define NWH   12288  // NWIN * HEADS

// ---------------- bias table: bias[head][n][m] ----------------
// NOTE (round 5 fix): reference applies sign*log1p transform to (d + win-1),
// i.e. to dy+6 in [0,12], NOT to raw dy. Values saturate at 12 for dy >= -2.
__global__ void k_bias(const float* __restrict__ cpb, float* __restrict__ bias) {
  int idx = blockIdx.x * 256 + threadIdx.x;
  if (idx >= HEADS * NPIX * NPIX) return;
  int m = idx % NPIX;
  int n = (idx / NPIX) % NPIX;
  int h = idx / (NPIX * NPIX);
  int sy = (n / WIN - m / WIN) + (WIN - 1);   // in [0,12]
  int sx = (n % WIN - m % WIN) + (WIN - 1);   // in [0,12]
  const double inv_log_beta = 1.0 / log(1.3);
  double fy = (sy == 0 ? 0.0 : log1p((double)sy) * inv_log_beta) + 6.0;
  double fx = (sx == 0 ? 0.0 : log1p((double)sx) * inv_log_beta) + 6.0;
  fy = fmin(12.0, fmax(0.0, fy));
  fx = fmin(12.0, fmax(0.0, fx));
  int ridx = (int)(fy * 13.0 + fx);
  bias[idx] = cpb[ridx * HEADS + h];
}

// ---------------- fused QKV projection + window attention ----------------
// grid (12, 1024): blockIdx.x = head, blockIdx.y = window
// Pure fp32 end-to-end; q,k,v live only in LDS.
__global__ __launch_bounds__(256) void k_fused(const float* __restrict__ x,
                                               const float* __restrict__ wqkv,
                                               const float* __restrict__ bias,
                                               float* __restrict__ y) {
  __shared__ int   spix[NPIX];
  __shared__ float sx[32][NPIX];     //  6.3 KB  x chunk (32 channels)
  __shared__ float sw[96][33];       // 12.7 KB  w chunk (96 rows x 32 c)
  __shared__ float sqkv[96][50];     // 19.2 KB  q(0..31) k(32..63) v(64..95)
  __shared__ float sl[NPIX][50];     //  9.8 KB  logits / probs

  int t  = threadIdx.x;
  int h  = blockIdx.x;
  int wb = blockIdx.y;
  int b = wb >> 6, gy = (wb >> 3) & 7, gx = wb & 7;

  if (t < NPIX) {
    int wy = t / WIN, wx = t - (t / WIN) * WIN;
    int hh = (gy * WIN + wy + 4) % IMG;
    int ww = (gx * WIN + wx + 4) % IMG;
    spix[t] = hh * IMG + ww;
  }
  __syncthreads();

  const float* xb = x + (size_t)b * DIM * (IMG * IMG);

  // GEMM thread map: 240 active threads: ro = t%24, co = t/24 (0..9)
  int ro = t % 24, co = t / 24;
  int nl[5];
  for (int j = 0; j < 5; ++j) {
    int n = co * 5 + j;
    nl[j] = (n > 48) ? 48 : n;
  }
  float acc[4][5] = {};

  for (int c0 = 0; c0 < DIM; c0 += 32) {
    for (int idx = t; idx < 32 * NPIX; idx += 256) {
      int cc = idx / NPIX, n = idx - cc * NPIX;
      sx[cc][n] = xb[(size_t)(c0 + cc) * (IMG * IMG) + spix[n]];
    }
    for (int idx = t; idx < 96 * 32; idx += 256) {
      int r = idx >> 5, cc = idx & 31;
      int wr = (r >> 5) * DIM + h * HD + (r & 31);
      sw[r][cc] = wqkv[(size_t)wr * DIM + c0 + cc];
    }
    __syncthreads();
    if (t < 240) {
      for (int cc = 0; cc < 32; ++cc) {
        float wv[4], xv[5];
        for (int rr = 0; rr < 4; ++rr) wv[rr] = sw[ro + 24 * rr][cc];
        for (int j = 0; j < 5; ++j)  xv[j] = sx[cc][nl[j]];
        for (int rr = 0; rr < 4; ++rr)
          for (int j = 0; j < 5; ++j)
            acc[rr][j] += wv[rr] * xv[j];
      }
    }
    __syncthreads();
  }
  if (t < 240) {
    for (int rr = 0; rr < 4; ++rr)
      for (int j = 0; j < 5; ++j)
        sqkv[ro + 24 * rr][nl[j]] = acc[rr][j];
  }
  __syncthreads();

  // logits: sl[n][m] = scale * q_n . k_m + bias   (fp32)
  const float scale = 0.17677669529663687f;  // 32^-0.5
  const float* bh = bias + h * NPIX * NPIX;
  for (int idx = t; idx < NPIX * NPIX; idx += 256) {
    int n = idx / NPIX, m = idx - n * NPIX;
    float s = 0.f;
    for (int dd = 0; dd < HD; ++dd) s += sqkv[dd][n] * sqkv[32 + dd][m];
    sl[n][m] = s * scale + bh[idx];
  }
  __syncthreads();

  // softmax per row (fp32)
  if (t < NPIX) {
    float mx = -1e30f;
    for (int m = 0; m < NPIX; ++m) mx = fmaxf(mx, sl[t][m]);
    float sum = 0.f;
    for (int m = 0; m < NPIX; ++m) { float e = expf(sl[t][m] - mx); sl[t][m] = e; sum += e; }
    float r = 1.f / sum;
    for (int m = 0; m < NPIX; ++m) sl[t][m] *= r;
  }
  __syncthreads();

  // y[n][dd] = sum_m P[n][m] v[m][dd]
  size_t ybase = (size_t)(wb * HEADS + h) * NPIX * HD;
  for (int idx = t; idx < NPIX * HD; idx += 256) {
    int n = idx >> 5, dd = idx & 31;
    float a = 0.f;
    for (int m = 0; m < NPIX; ++m) a += sl[n][m] * sqkv[64 + dd][m];
    y[ybase + idx] = a;
  }
}

// ---------------- output projection (scatter with inverse shift) ----------------
__global__ __launch_bounds__(256) void k_proj(const float* __restrict__ y,
                                              const float* __restrict__ wproj,
                                              float* __restrict__ out) {
  __shared__ float sw[64][65];
  __shared__ float sy[64][50];
  int t  = threadIdx.x;
  int wb = blockIdx.y;
  int o0 = blockIdx.x * 64;
  int b = wb >> 6, gy = (wb >> 3) & 7, gx = wb & 7;
  int tn = t & 15, to = t >> 4;
  int nj = (tn == 0) ? 4 : 3;
  int nlist[4], pix3[4];
  for (int j = 0; j < 4; ++j) {
    int n = tn + 16 * j;
    if (n > 48) n = 48;
    nlist[j] = n;
    int wy = n / WIN, wx = n - wy * WIN;
    int hh = (gy * WIN + wy + 3) % IMG;
    int ww = (gx * WIN + wx + 3) % IMG;
    pix3[j] = hh * IMG + ww;
  }
  float acc[4][4] = {};
  for (int k0 = 0; k0 < DIM; k0 += 64) {
    for (int i = 0; i < 16; ++i) {
      int idx = t + 256 * i;
      int o = idx >> 6, kk = idx & 63;
      sw[o][kk] = wproj[(size_t)(o0 + o) * DIM + k0 + kk];
    }
    for (int i = 0; i < 13; ++i) {
      int idx = t + 256 * i;
      if (idx < 64 * NPIX) {
        int n = idx >> 6, kk = idx & 63;
        int c = k0 + kk;
        sy[kk][n] = y[((size_t)(wb * HEADS + (c >> 5)) * NPIX + n) * HD + (c & 31)];
      }
    }
    __syncthreads();
    for (int kk = 0; kk < 64; ++kk) {
      float wv[4], xv[4];
      for (int r = 0; r < 4; ++r) wv[r] = sw[to * 4 + r][kk];
      for (int j = 0; j < 4; ++j) xv[j] = sy[kk][nlist[j]];
      for (int r = 0; r < 4; ++r)
        for (int j = 0; j < 4; ++j)
          acc[r][j] += wv[r] * xv[j];
    }
    __syncthreads();
  }
  for (int r = 0; r < 4; ++r) {
    int o = o0 + to * 4 + r;
    for (int j = 0; j < nj; ++j) {
      out[(size_t)(b * DIM + o) * (IMG * IMG) + pix3[j]] = acc[r][j];
    }
  }
}

extern "C" void kernel_launch(void* const* d_in, const int* in_sizes, int n_in,
                              void* d_out, int out_size, void* d_ws, size_t ws_size,
                              hipStream_t stream) {
  const float* x     = (const float*)d_in[0];
  const float* wqkv  = (const float*)d_in[1];
  const float* wproj = (const float*)d_in[2];
  const float* cpb   = (const float*)d_in[3];
  float* out = (float*)d_out;

  char* ws = (char*)d_ws;
  float* bias = (float*)ws;                 // 115 KB
  float* yb   = (float*)(ws + 131072);      // 12288*49*32*4 = 77.07 MB

  hipLaunchKernelGGL(k_bias, dim3((HEADS * NPIX * NPIX + 255) / 256), dim3(256), 0, stream,
                     cpb, bias);
  hipLaunchKernelGGL(k_fused, dim3(HEADS, NWIN), dim3(256), 0, stream, x, wqkv, bias, yb);
  hipLaunchKernelGGL(k_proj, dim3(6, NWIN), dim3(256), 0, stream, yb, wproj, out);
}

// Round 7
// 746.200 us; speedup vs baseline: 3.8013x; 3.8013x over previous
//
#include <hip/hip_runtime.h>
#include <hip/hip_bf16.h>
#include <math.h>

#define DIM   384
#define HEADS 12
#define HD    32
#define WIN   7
#define NPIX  49
#define IMG   56
#define NPF   3136   // IMG*IMG
#define NWIN  1024

typedef __attribute__((ext_vector_type(8))) short short8;
typedef __attribute__((ext_vector_type(4))) float f32x4;
#define MFMA __builtin_amdgcn_mfma_f32_16x16x32_bf16

__device__ inline ushort tob(float f) {
  unsigned u; __builtin_memcpy(&u, &f, 4);
  u += 0x7fffu + ((u >> 16) & 1u);
  return (ushort)(u >> 16);
}
__device__ inline float fromb(ushort h) {
  unsigned u = ((unsigned)h) << 16; float f; __builtin_memcpy(&f, &u, 4); return f;
}

// ---------------- bias table: bias[head][n][m] (fixed transform: d+6 input) ----
__global__ void k_bias(const float* __restrict__ cpb, float* __restrict__ bias) {
  int idx = blockIdx.x * 256 + threadIdx.x;
  if (idx >= HEADS * NPIX * NPIX) return;
  int m = idx % NPIX;
  int n = (idx / NPIX) % NPIX;
  int h = idx / (NPIX * NPIX);
  int sy = (n / WIN - m / WIN) + (WIN - 1);
  int sx = (n % WIN - m % WIN) + (WIN - 1);
  const double inv_log_beta = 1.0 / log(1.3);
  double fy = (sy == 0 ? 0.0 : log1p((double)sy) * inv_log_beta) + 6.0;
  double fx = (sx == 0 ? 0.0 : log1p((double)sx) * inv_log_beta) + 6.0;
  fy = fmin(12.0, fmax(0.0, fy));
  fx = fmin(12.0, fmax(0.0, fx));
  int ridx = (int)(fy * 13.0 + fx);
  bias[idx] = cpb[ridx * HEADS + h];
}

// rolled-pixel map: rmap[p] = rolled(+4,+4) source pixel
__global__ void k_rmap(int* __restrict__ rmap) {
  int p = blockIdx.x * 256 + threadIdx.x;
  if (p < NPF) {
    int i = p / IMG, j = p % IMG;
    rmap[p] = ((i + 4) % IMG) * IMG + ((j + 4) % IMG);
  }
}

// ---------------- QKV projection: MFMA GEMM  qkv[b][o][p] = W[o][:] . Xr[:][p]
// grid (9 otiles, 25 ptiles, 16 batch), 256 threads = 4 waves (2x2 of 64x64)
__global__ __launch_bounds__(256) void k_qkv(const float* __restrict__ x,
                                             const float* __restrict__ wqkv,
                                             const int* __restrict__ rmap,
                                             ushort* __restrict__ qkv) {
  __shared__ __align__(16) ushort sA[2][128 * 40];
  __shared__ __align__(16) ushort sB[2][128 * 40];
  __shared__ int srm[128];
  int t  = threadIdx.x;
  int o0 = blockIdx.x * 128;
  int p0 = blockIdx.y * 128;
  int b  = blockIdx.z;
  if (t < 128) { int pg = p0 + t; srm[t] = (pg < NPF) ? rmap[pg] : 0; }
  __syncthreads();

  int lane = t & 63, w = t >> 6;
  int wm = w >> 1, wn = w & 1;
  int l15 = lane & 15, l4 = lane >> 4;

  int ak = t & 31, ao = (t >> 5) << 4;    // A stage: this thread: col k0+ak, rows ao..ao+15
  int bp = t & 127, bc = (t >> 7) << 4;   // B stage: this thread: pixel bp, chans bc..bc+15

  const float* xb = x + (size_t)b * DIM * NPF;

  f32x4 acc[4][4] = {};
  float av[16], bv[16];

  // prologue: stage k-step 0
  for (int i = 0; i < 16; ++i) av[i] = wqkv[(size_t)(o0 + ao + i) * DIM + ak];
  for (int i = 0; i < 16; ++i) bv[i] = xb[(size_t)(bc + i) * NPF + srm[bp]];
  for (int i = 0; i < 16; ++i) sA[0][(ao + i) * 40 + ak] = tob(av[i]);
  for (int i = 0; i < 16; ++i) sB[0][bp * 40 + bc + i] = tob(bv[i]);

  for (int ks = 0; ks < 12; ++ks) {
    __syncthreads();
    int cur = ks & 1;
    if (ks < 11) {
      int k0 = (ks + 1) * 32;
      for (int i = 0; i < 16; ++i) av[i] = wqkv[(size_t)(o0 + ao + i) * DIM + k0 + ak];
      for (int i = 0; i < 16; ++i) bv[i] = xb[(size_t)(k0 + bc + i) * NPF + srm[bp]];
    }
    short8 af[4], bfr[4];
    for (int mi = 0; mi < 4; ++mi)
      af[mi] = *(const short8*)&sA[cur][(wm * 64 + mi * 16 + l15) * 40 + l4 * 8];
    for (int ni = 0; ni < 4; ++ni)
      bfr[ni] = *(const short8*)&sB[cur][(wn * 64 + ni * 16 + l15) * 40 + l4 * 8];
    for (int mi = 0; mi < 4; ++mi)
      for (int ni = 0; ni < 4; ++ni)
        acc[mi][ni] = MFMA(af[mi], bfr[ni], acc[mi][ni], 0, 0, 0);
    if (ks < 11) {
      int nxt = cur ^ 1;
      for (int i = 0; i < 16; ++i) sA[nxt][(ao + i) * 40 + ak] = tob(av[i]);
      for (int i = 0; i < 16; ++i) sB[nxt][bp * 40 + bc + i] = tob(bv[i]);
    }
  }

  for (int mi = 0; mi < 4; ++mi)
    for (int ni = 0; ni < 4; ++ni)
      for (int r = 0; r < 4; ++r) {
        int o = o0 + wm * 64 + mi * 16 + (l4 << 2) + r;
        int p = p0 + wn * 64 + ni * 16 + l15;
        if (p < NPF)
          qkv[((size_t)b * 1152 + o) * NPF + p] = tob(acc[mi][ni][r]);
      }
}

// ---------------- MFMA attention per (window, head), 1 wave ----------------
__global__ __launch_bounds__(64) void k_attn(ushort* __restrict__ qkv,
                                             const float* __restrict__ bias) {
  __shared__ __align__(16) ushort smem[13794];
  ushort* sq  = smem;                   // [64][40] bf16
  ushort* skt = smem + 2560;            // [64][40]
  ushort* svt = smem + 5120;            // [32][72]  V transposed [d][m]
  float*  sl  = (float*)(smem + 7424);  // [49][65] f32 logits
  ushort* pa  = smem;                   // [64][72] P bf16 (overlays sq/skt)

  int t = threadIdx.x;
  int bid = blockIdx.x;
  int h = bid % HEADS, wb = bid / HEADS;
  int b = wb >> 6, gy = (wb >> 3) & 7, gx = wb & 7;
  int pb = gy * 7 * IMG + gx * 7;
  size_t qb = ((size_t)b * 1152 + h * HD) * NPF;
  size_t kb = qb + (size_t)DIM * NPF;
  size_t vb = qb + (size_t)(2 * DIM) * NPF;

  int pix = pb + (t / 7) * IMG + (t % 7);
  if (t < NPIX) {
    for (int d = 0; d < HD; ++d) {
      sq [t * 40 + d] = qkv[qb + (size_t)d * NPF + pix];
      skt[t * 40 + d] = qkv[kb + (size_t)d * NPF + pix];
    }
  }
  for (int d = 0; d < HD; ++d)
    svt[d * 72 + t] = (t < NPIX) ? qkv[vb + (size_t)d * NPF + pix] : (ushort)0;
  __syncthreads();

  int l15 = t & 15, l4 = t >> 4;
  f32x4 acc[4][4] = {};
  {
    short8 af[4], bfr[4];
    for (int mi = 0; mi < 4; ++mi) af[mi]  = *(const short8*)&sq [(mi * 16 + l15) * 40 + l4 * 8];
    for (int ni = 0; ni < 4; ++ni) bfr[ni] = *(const short8*)&skt[(ni * 16 + l15) * 40 + l4 * 8];
    for (int mi = 0; mi < 4; ++mi)
      for (int ni = 0; ni < 4; ++ni)
        acc[mi][ni] = MFMA(af[mi], bfr[ni], acc[mi][ni], 0, 0, 0);
  }

  const float scale = 0.17677669529663687f;
  const float* bh = bias + h * NPIX * NPIX;
  for (int mi = 0; mi < 4; ++mi)
    for (int ni = 0; ni < 4; ++ni)
      for (int r = 0; r < 4; ++r) {
        int n = mi * 16 + (l4 << 2) + r;
        int m = ni * 16 + l15;
        if (n < NPIX)
          sl[n * 65 + m] = (m < NPIX) ? acc[mi][ni][r] * scale + bh[n * NPIX + m] : -1e30f;
      }
  __syncthreads();

  if (t < NPIX) {
    float mx = -1e30f;
    for (int m = 0; m < 64; ++m) mx = fmaxf(mx, sl[t * 65 + m]);
    float s = 0.f;
    for (int m = 0; m < 64; ++m) { float e = expf(sl[t * 65 + m] - mx); sl[t * 65 + m] = e; s += e; }
    float ri = 1.f / s;
    for (int m = 0; m < 64; ++m) pa[t * 72 + m] = tob(sl[t * 65 + m] * ri);
  } else {
    for (int m = 0; m < 64; ++m) pa[t * 72 + m] = 0;
  }
  __syncthreads();

  f32x4 yac[4][2] = {};
  for (int ks = 0; ks < 2; ++ks) {
    short8 pf[4], vf[2];
    for (int mi = 0; mi < 4; ++mi) pf[mi] = *(const short8*)&pa [(mi * 16 + l15) * 72 + ks * 32 + l4 * 8];
    for (int nd = 0; nd < 2; ++nd) vf[nd] = *(const short8*)&svt[(nd * 16 + l15) * 72 + ks * 32 + l4 * 8];
    for (int mi = 0; mi < 4; ++mi)
      for (int nd = 0; nd < 2; ++nd)
        yac[mi][nd] = MFMA(pf[mi], vf[nd], yac[mi][nd], 0, 0, 0);
  }
  for (int mi = 0; mi < 4; ++mi)
    for (int nd = 0; nd < 2; ++nd)
      for (int r = 0; r < 4; ++r) {
        int n = mi * 16 + (l4 << 2) + r;
        if (n < NPIX) {
          int d = nd * 16 + l15;
          int px = pb + (n / 7) * IMG + (n % 7);
          qkv[qb + (size_t)d * NPF + px] = tob(yac[mi][nd][r]);  // Y over Q slice
        }
      }
}

// ---------------- output projection (VALU, reads Y from qkv Q-region) --------
__global__ __launch_bounds__(256) void k_proj(const ushort* __restrict__ yq,
                                              const float* __restrict__ wproj,
                                              float* __restrict__ out) {
  __shared__ float sw[64][65];
  __shared__ float sy[64][50];
  __shared__ int spix[NPIX];
  int t  = threadIdx.x;
  int wb = blockIdx.y;
  int o0 = blockIdx.x * 64;
  int b = wb >> 6, gy = (wb >> 3) & 7, gx = wb & 7;
  if (t < NPIX) spix[t] = (gy * 7 + t / 7) * IMG + gx * 7 + t % 7;
  __syncthreads();
  int tn = t & 15, to = t >> 4;
  int nj = (tn == 0) ? 4 : 3;
  int nlist[4], pix3[4];
  for (int j = 0; j < 4; ++j) {
    int n = tn + 16 * j;
    if (n > 48) n = 48;
    nlist[j] = n;
    int wy = n / WIN, wx = n - wy * WIN;
    int hh = (gy * WIN + wy + 3) % IMG;
    int ww = (gx * WIN + wx + 3) % IMG;
    pix3[j] = hh * IMG + ww;
  }
  float acc[4][4] = {};
  for (int k0 = 0; k0 < DIM; k0 += 64) {
    for (int i = 0; i < 16; ++i) {
      int idx = t + 256 * i;
      int o = idx >> 6, kk = idx & 63;
      sw[o][kk] = wproj[(size_t)(o0 + o) * DIM + k0 + kk];
    }
    for (int i = 0; i < 13; ++i) {
      int idx = t + 256 * i;
      if (idx < 64 * NPIX) {
        int kk = idx / NPIX, n = idx - kk * NPIX;
        sy[kk][n] = fromb(yq[((size_t)b * 1152 + k0 + kk) * NPF + spix[n]]);
      }
    }
    __syncthreads();
    for (int kk = 0; kk < 64; ++kk) {
      float wv[4], xv[4];
      for (int r = 0; r < 4; ++r) wv[r] = sw[to * 4 + r][kk];
      for (int j = 0; j < 4; ++j) xv[j] = sy[kk][nlist[j]];
      for (int r = 0; r < 4; ++r)
        for (int j = 0; j < 4; ++j)
          acc[r][j] += wv[r] * xv[j];
    }
    __syncthreads();
  }
  for (int r = 0; r < 4; ++r) {
    int o = o0 + to * 4 + r;
    for (int j = 0; j < nj; ++j) {
      out[(size_t)(b * DIM + o) * NPF + pix3[j]] = acc[r][j];
    }
  }
}

extern "C" void kernel_launch(void* const* d_in, const int* in_sizes, int n_in,
                              void* d_out, int out_size, void* d_ws, size_t ws_size,
                              hipStream_t stream) {
  const float* x     = (const float*)d_in[0];
  const float* wqkv  = (const float*)d_in[1];
  const float* wproj = (const float*)d_in[2];
  const float* cpb   = (const float*)d_in[3];
  float* out = (float*)d_out;

  char* ws = (char*)d_ws;
  float* bias  = (float*)ws;                 // 28812 f32 = 115248 B
  int*   rmap  = (int*)(ws + 115712);        // 3136 int  -> ends 128256
  ushort* qkv  = (ushort*)(ws + 131072);     // 16*1152*3136 bf16 = 115.6 MB

  hipLaunchKernelGGL(k_bias, dim3(113), dim3(256), 0, stream, cpb, bias);
  hipLaunchKernelGGL(k_rmap, dim3(13), dim3(256), 0, stream, rmap);
  hipLaunchKernelGGL(k_qkv, dim3(9, 25, 16), dim3(256), 0, stream, x, wqkv, rmap, qkv);
  hipLaunchKernelGGL(k_attn, dim3(NWIN * HEADS), dim3(64), 0, stream, qkv, bias);
  hipLaunchKernelGGL(k_proj, dim3(6, NWIN), dim3(256), 0, stream, qkv, wproj, out);
}

// Round 8
// 441.502 us; speedup vs baseline: 6.4248x; 1.6901x over previous
//
#include <hip/hip_runtime.h>
#include <hip/hip_bf16.h>
#include <math.h>

#define DIM   384
#define HEADS 12
#define HD    32
#define WIN   7
#define NPIX  49
#define IMG   56
#define NPF   3136   // IMG*IMG
#define NWIN  1024

typedef __attribute__((ext_vector_type(8))) short short8;
typedef __attribute__((ext_vector_type(4))) float f32x4;
#define MFMA __builtin_amdgcn_mfma_f32_16x16x32_bf16

__device__ inline ushort tob(float f) {
  unsigned u; __builtin_memcpy(&u, &f, 4);
  u += 0x7fffu + ((u >> 16) & 1u);
  return (ushort)(u >> 16);
}
__device__ inline float fromb(ushort h) {
  unsigned u = ((unsigned)h) << 16; float f; __builtin_memcpy(&f, &u, 4); return f;
}

// ---------------- bias table: bias[head][n][m] (fixed transform: d+6 input) ----
__global__ void k_bias(const float* __restrict__ cpb, float* __restrict__ bias) {
  int idx = blockIdx.x * 256 + threadIdx.x;
  if (idx >= HEADS * NPIX * NPIX) return;
  int m = idx % NPIX;
  int n = (idx / NPIX) % NPIX;
  int h = idx / (NPIX * NPIX);
  int sy = (n / WIN - m / WIN) + (WIN - 1);
  int sx = (n % WIN - m % WIN) + (WIN - 1);
  const double inv_log_beta = 1.0 / log(1.3);
  double fy = (sy == 0 ? 0.0 : log1p((double)sy) * inv_log_beta) + 6.0;
  double fx = (sx == 0 ? 0.0 : log1p((double)sx) * inv_log_beta) + 6.0;
  fy = fmin(12.0, fmax(0.0, fy));
  fx = fmin(12.0, fmax(0.0, fx));
  int ridx = (int)(fy * 13.0 + fx);
  bias[idx] = cpb[ridx * HEADS + h];
}

// rolled-pixel map: rmap[p] = rolled(+4,+4) source pixel
__global__ void k_rmap(int* __restrict__ rmap) {
  int p = blockIdx.x * 256 + threadIdx.x;
  if (p < NPF) {
    int i = p / IMG, j = p % IMG;
    rmap[p] = ((i + 4) % IMG) * IMG + ((j + 4) % IMG);
  }
}

// ---------------- QKV projection: MFMA GEMM  qkv[b][o][p] = W[o][:] . Xr[:][p]
// grid (9 otiles, 25 ptiles, 16 batch), 256 threads = 4 waves (2x2 of 64x64)
__global__ __launch_bounds__(256) void k_qkv(const float* __restrict__ x,
                                             const float* __restrict__ wqkv,
                                             const int* __restrict__ rmap,
                                             ushort* __restrict__ qkv) {
  __shared__ __align__(16) ushort sA[2][128 * 40];
  __shared__ __align__(16) ushort sB[2][128 * 40];
  __shared__ int srm[128];
  int t  = threadIdx.x;
  int o0 = blockIdx.x * 128;
  int p0 = blockIdx.y * 128;
  int b  = blockIdx.z;
  if (t < 128) { int pg = p0 + t; srm[t] = (pg < NPF) ? rmap[pg] : 0; }
  __syncthreads();

  int lane = t & 63, w = t >> 6;
  int wm = w >> 1, wn = w & 1;
  int l15 = lane & 15, l4 = lane >> 4;

  int ak = t & 31, ao = (t >> 5) << 4;
  int bp = t & 127, bc = (t >> 7) << 4;

  const float* xb = x + (size_t)b * DIM * NPF;

  f32x4 acc[4][4] = {};
  float av[16], bv[16];

  for (int i = 0; i < 16; ++i) av[i] = wqkv[(size_t)(o0 + ao + i) * DIM + ak];
  for (int i = 0; i < 16; ++i) bv[i] = xb[(size_t)(bc + i) * NPF + srm[bp]];
  for (int i = 0; i < 16; ++i) sA[0][(ao + i) * 40 + ak] = tob(av[i]);
  for (int i = 0; i < 16; ++i) sB[0][bp * 40 + bc + i] = tob(bv[i]);

  for (int ks = 0; ks < 12; ++ks) {
    __syncthreads();
    int cur = ks & 1;
    if (ks < 11) {
      int k0 = (ks + 1) * 32;
      for (int i = 0; i < 16; ++i) av[i] = wqkv[(size_t)(o0 + ao + i) * DIM + k0 + ak];
      for (int i = 0; i < 16; ++i) bv[i] = xb[(size_t)(k0 + bc + i) * NPF + srm[bp]];
    }
    short8 af[4], bfr[4];
    for (int mi = 0; mi < 4; ++mi)
      af[mi] = *(const short8*)&sA[cur][(wm * 64 + mi * 16 + l15) * 40 + l4 * 8];
    for (int ni = 0; ni < 4; ++ni)
      bfr[ni] = *(const short8*)&sB[cur][(wn * 64 + ni * 16 + l15) * 40 + l4 * 8];
    for (int mi = 0; mi < 4; ++mi)
      for (int ni = 0; ni < 4; ++ni)
        acc[mi][ni] = MFMA(af[mi], bfr[ni], acc[mi][ni], 0, 0, 0);
    if (ks < 11) {
      int nxt = cur ^ 1;
      for (int i = 0; i < 16; ++i) sA[nxt][(ao + i) * 40 + ak] = tob(av[i]);
      for (int i = 0; i < 16; ++i) sB[nxt][bp * 40 + bc + i] = tob(bv[i]);
    }
  }

  for (int mi = 0; mi < 4; ++mi)
    for (int ni = 0; ni < 4; ++ni)
      for (int r = 0; r < 4; ++r) {
        int o = o0 + wm * 64 + mi * 16 + (l4 << 2) + r;
        int p = p0 + wn * 64 + ni * 16 + l15;
        if (p < NPF)
          qkv[((size_t)b * 1152 + o) * NPF + p] = tob(acc[mi][ni][r]);
      }
}

// ---------------- MFMA attention per (window, head), 1 wave ----------------
__global__ __launch_bounds__(64) void k_attn(ushort* __restrict__ qkv,
                                             const float* __restrict__ bias) {
  __shared__ __align__(16) ushort smem[13794];
  ushort* sq  = smem;                   // [64][40] bf16
  ushort* skt = smem + 2560;            // [64][40]
  ushort* svt = smem + 5120;            // [32][72]  V transposed [d][m]
  float*  sl  = (float*)(smem + 7424);  // [49][65] f32 logits
  ushort* pa  = smem;                   // [64][72] P bf16 (overlays sq/skt)

  int t = threadIdx.x;
  int bid = blockIdx.x;
  int h = bid % HEADS, wb = bid / HEADS;
  int b = wb >> 6, gy = (wb >> 3) & 7, gx = wb & 7;
  int pb = gy * 7 * IMG + gx * 7;
  size_t qb = ((size_t)b * 1152 + h * HD) * NPF;
  size_t kb = qb + (size_t)DIM * NPF;
  size_t vb = qb + (size_t)(2 * DIM) * NPF;

  int pix = pb + (t / 7) * IMG + (t % 7);
  if (t < NPIX) {
    for (int d = 0; d < HD; ++d) {
      sq [t * 40 + d] = qkv[qb + (size_t)d * NPF + pix];
      skt[t * 40 + d] = qkv[kb + (size_t)d * NPF + pix];
    }
  }
  for (int d = 0; d < HD; ++d)
    svt[d * 72 + t] = (t < NPIX) ? qkv[vb + (size_t)d * NPF + pix] : (ushort)0;
  __syncthreads();

  int l15 = t & 15, l4 = t >> 4;
  f32x4 acc[4][4] = {};
  {
    short8 af[4], bfr[4];
    for (int mi = 0; mi < 4; ++mi) af[mi]  = *(const short8*)&sq [(mi * 16 + l15) * 40 + l4 * 8];
    for (int ni = 0; ni < 4; ++ni) bfr[ni] = *(const short8*)&skt[(ni * 16 + l15) * 40 + l4 * 8];
    for (int mi = 0; mi < 4; ++mi)
      for (int ni = 0; ni < 4; ++ni)
        acc[mi][ni] = MFMA(af[mi], bfr[ni], acc[mi][ni], 0, 0, 0);
  }

  const float scale = 0.17677669529663687f;
  const float* bh = bias + h * NPIX * NPIX;
  for (int mi = 0; mi < 4; ++mi)
    for (int ni = 0; ni < 4; ++ni)
      for (int r = 0; r < 4; ++r) {
        int n = mi * 16 + (l4 << 2) + r;
        int m = ni * 16 + l15;
        if (n < NPIX)
          sl[n * 65 + m] = (m < NPIX) ? acc[mi][ni][r] * scale + bh[n * NPIX + m] : -1e30f;
      }
  __syncthreads();

  if (t < NPIX) {
    float mx = -1e30f;
    for (int m = 0; m < 64; ++m) mx = fmaxf(mx, sl[t * 65 + m]);
    float s = 0.f;
    for (int m = 0; m < 64; ++m) { float e = expf(sl[t * 65 + m] - mx); sl[t * 65 + m] = e; s += e; }
    float ri = 1.f / s;
    for (int m = 0; m < 64; ++m) pa[t * 72 + m] = tob(sl[t * 65 + m] * ri);
  } else {
    for (int m = 0; m < 64; ++m) pa[t * 72 + m] = 0;
  }
  __syncthreads();

  f32x4 yac[4][2] = {};
  for (int ks = 0; ks < 2; ++ks) {
    short8 pf[4], vf[2];
    for (int mi = 0; mi < 4; ++mi) pf[mi] = *(const short8*)&pa [(mi * 16 + l15) * 72 + ks * 32 + l4 * 8];
    for (int nd = 0; nd < 2; ++nd) vf[nd] = *(const short8*)&svt[(nd * 16 + l15) * 72 + ks * 32 + l4 * 8];
    for (int mi = 0; mi < 4; ++mi)
      for (int nd = 0; nd < 2; ++nd)
        yac[mi][nd] = MFMA(pf[mi], vf[nd], yac[mi][nd], 0, 0, 0);
  }
  for (int mi = 0; mi < 4; ++mi)
    for (int nd = 0; nd < 2; ++nd)
      for (int r = 0; r < 4; ++r) {
        int n = mi * 16 + (l4 << 2) + r;
        if (n < NPIX) {
          int d = nd * 16 + l15;
          int px = pb + (n / 7) * IMG + (n % 7);
          qkv[qb + (size_t)d * NPF + px] = tob(yac[mi][nd][r]);  // Y over Q slice
        }
      }
}

// ---------------- output projection: MFMA GEMM out[b][o][p] = Wp . Y ----------
// grid (3 otiles, 25 ptiles, 16 batch), 256 threads = 4 waves (2x2 of 64x64)
// Inverse roll (+3) folded into the B gather: out pixel p reads Y at (p-3)%56.
__global__ __launch_bounds__(256) void k_proj(const ushort* __restrict__ yq,
                                              const float* __restrict__ wproj,
                                              float* __restrict__ out) {
  __shared__ __align__(16) ushort sA[2][128 * 40];
  __shared__ __align__(16) ushort sB[2][128 * 40];
  __shared__ int srm[128];
  int t  = threadIdx.x;
  int o0 = blockIdx.x * 128;
  int p0 = blockIdx.y * 128;
  int b  = blockIdx.z;
  if (t < 128) {
    int pg = p0 + t;
    if (pg >= NPF) pg = 0;
    int i = pg / IMG, j = pg - (pg / IMG) * IMG;
    srm[t] = ((i + 53) % IMG) * IMG + ((j + 53) % IMG);   // -3 mod 56
  }
  __syncthreads();

  int lane = t & 63, w = t >> 6;
  int wm = w >> 1, wn = w & 1;
  int l15 = lane & 15, l4 = lane >> 4;

  int ak = t & 31, ao = (t >> 5) << 4;
  int bp = t & 127, bc = (t >> 7) << 4;

  const ushort* yb = yq + (size_t)b * 1152 * NPF;

  f32x4 acc[4][4] = {};
  float av[16];
  ushort bv[16];

  for (int i = 0; i < 16; ++i) av[i] = wproj[(size_t)(o0 + ao + i) * DIM + ak];
  for (int i = 0; i < 16; ++i) bv[i] = yb[(size_t)(bc + i) * NPF + srm[bp]];
  for (int i = 0; i < 16; ++i) sA[0][(ao + i) * 40 + ak] = tob(av[i]);
  for (int i = 0; i < 16; ++i) sB[0][bp * 40 + bc + i] = bv[i];

  for (int ks = 0; ks < 12; ++ks) {
    __syncthreads();
    int cur = ks & 1;
    if (ks < 11) {
      int k0 = (ks + 1) * 32;
      for (int i = 0; i < 16; ++i) av[i] = wproj[(size_t)(o0 + ao + i) * DIM + k0 + ak];
      for (int i = 0; i < 16; ++i) bv[i] = yb[(size_t)(k0 + bc + i) * NPF + srm[bp]];
    }
    short8 af[4], bfr[4];
    for (int mi = 0; mi < 4; ++mi)
      af[mi] = *(const short8*)&sA[cur][(wm * 64 + mi * 16 + l15) * 40 + l4 * 8];
    for (int ni = 0; ni < 4; ++ni)
      bfr[ni] = *(const short8*)&sB[cur][(wn * 64 + ni * 16 + l15) * 40 + l4 * 8];
    for (int mi = 0; mi < 4; ++mi)
      for (int ni = 0; ni < 4; ++ni)
        acc[mi][ni] = MFMA(af[mi], bfr[ni], acc[mi][ni], 0, 0, 0);
    if (ks < 11) {
      int nxt = cur ^ 1;
      for (int i = 0; i < 16; ++i) sA[nxt][(ao + i) * 40 + ak] = tob(av[i]);
      for (int i = 0; i < 16; ++i) sB[nxt][bp * 40 + bc + i] = bv[i];
    }
  }

  for (int mi = 0; mi < 4; ++mi)
    for (int ni = 0; ni < 4; ++ni)
      for (int r = 0; r < 4; ++r) {
        int o = o0 + wm * 64 + mi * 16 + (l4 << 2) + r;
        int p = p0 + wn * 64 + ni * 16 + l15;
        if (p < NPF)
          out[((size_t)b * DIM + o) * NPF + p] = acc[mi][ni][r];
      }
}

extern "C" void kernel_launch(void* const* d_in, const int* in_sizes, int n_in,
                              void* d_out, int out_size, void* d_ws, size_t ws_size,
                              hipStream_t stream) {
  const float* x     = (const float*)d_in[0];
  const float* wqkv  = (const float*)d_in[1];
  const float* wproj = (const float*)d_in[2];
  const float* cpb   = (const float*)d_in[3];
  float* out = (float*)d_out;

  char* ws = (char*)d_ws;
  float* bias  = (float*)ws;                 // 28812 f32 = 115248 B
  int*   rmap  = (int*)(ws + 115712);        // 3136 int  -> ends 128256
  ushort* qkv  = (ushort*)(ws + 131072);     // 16*1152*3136 bf16 = 115.6 MB

  hipLaunchKernelGGL(k_bias, dim3(113), dim3(256), 0, stream, cpb, bias);
  hipLaunchKernelGGL(k_rmap, dim3(13), dim3(256), 0, stream, rmap);
  hipLaunchKernelGGL(k_qkv, dim3(9, 25, 16), dim3(256), 0, stream, x, wqkv, rmap, qkv);
  hipLaunchKernelGGL(k_attn, dim3(NWIN * HEADS), dim3(64), 0, stream, qkv, bias);
  hipLaunchKernelGGL(k_proj, dim3(3, 25, 16), dim3(256), 0, stream, qkv, wproj, out);
}